// Round 5
// baseline (246.671 us; speedup 1.0000x reference)
//
#include <hip/hip_runtime.h>
#include <stdint.h>

// ---------------------------------------------------------------------------
// AbstractAttention  B=2,S=2048,H=16,Dh=64,Dm=1024. fp32 in/out, bf16 MFMA.
// R5: (1) PV via K=16 MFMA exploiting C-layout==B-frag(16x16x16) identity —
// removes the 16-bpermute P exchange (attn is LDS-pipe bound);
// (2) XCD-aware 1D block swizzle in GEMMs (A-panel L2 locality: all n-tiles
// of a panel share blockIdx%8); (3) single-barrier LDS double-buffering in
// gemm + attn (DMA for tile t+1 issued after barrier, drained after compute).
// ---------------------------------------------------------------------------

typedef __attribute__((ext_vector_type(8))) short short8;
typedef __attribute__((ext_vector_type(4))) short short4v;
typedef __attribute__((ext_vector_type(4))) float floatx4;
typedef __attribute__((ext_vector_type(4))) unsigned int uintx4;
typedef __attribute__((ext_vector_type(2))) unsigned int uint2v;

#define MFMA16(a, b, c) __builtin_amdgcn_mfma_f32_16x16x32_bf16(a, b, c, 0, 0, 0)

#if __has_builtin(__builtin_amdgcn_mfma_f32_16x16x16bf16_1k)
#define HAVE_K16 1
#define MFMAK16(a, b, c) __builtin_amdgcn_mfma_f32_16x16x16bf16_1k(a, b, c, 0, 0, 0)
#else
#define HAVE_K16 0
#endif

__device__ __forceinline__ unsigned short f2b(float f) {  // RNE fp32->bf16
  unsigned int u = __builtin_bit_cast(unsigned int, f);
  u = (u + 0x7fffu + ((u >> 16) & 1u)) >> 16;
  return (unsigned short)u;
}
__device__ __forceinline__ float exp2f_fast(float x) {
#if __has_builtin(__builtin_amdgcn_exp2f)
  return __builtin_amdgcn_exp2f(x);
#else
  return exp2f(x);
#endif
}
__device__ __forceinline__ unsigned int pack2_bf16(float lo, float hi) {
#if __has_builtin(__builtin_amdgcn_perm)
  return __builtin_amdgcn_perm(__builtin_bit_cast(unsigned int, hi),
                               __builtin_bit_cast(unsigned int, lo), 0x07060302u);
#else
  return (__builtin_bit_cast(unsigned int, lo) >> 16) |
         (__builtin_bit_cast(unsigned int, hi) & 0xffff0000u);
#endif
}

__device__ __forceinline__ void async_copy16(void* lds, const void* g) {
  __builtin_amdgcn_global_load_lds(
      (const __attribute__((address_space(1))) unsigned int*)g,
      (__attribute__((address_space(3))) unsigned int*)lds, 16, 0, 0);
}

// 4x4 transpose across lanes within col&3 groups (2 butterfly rounds).
__device__ __forceinline__ void xpose4(floatx4& v, int lane) {
  {
    float s0 = __shfl_xor(v[1], 1, 64);
    float s1 = __shfl_xor(v[0], 1, 64);
    float s2 = __shfl_xor(v[3], 1, 64);
    float s3 = __shfl_xor(v[2], 1, 64);
    if (lane & 1) { v[0] = s0; v[2] = s2; } else { v[1] = s1; v[3] = s3; }
  }
  {
    float s0 = __shfl_xor(v[2], 2, 64);
    float s1 = __shfl_xor(v[3], 2, 64);
    float s2 = __shfl_xor(v[0], 2, 64);
    float s3 = __shfl_xor(v[1], 2, 64);
    if (lane & 2) { v[0] = s0; v[1] = s1; } else { v[2] = s2; v[3] = s3; }
  }
}

// ---------------------------------------------------------------------------
// Conversions (unchanged)
// ---------------------------------------------------------------------------
__global__ __launch_bounds__(256) void conv_x3(const float* __restrict__ a,
                                               const float* __restrict__ b,
                                               const float* __restrict__ c,
                                               unsigned short* __restrict__ out) {
  const float* in = (blockIdx.y == 0) ? a : ((blockIdx.y == 1) ? b : c);
  size_t i = (size_t)blockIdx.x * 256 + threadIdx.x;
  float4 v = ((const float4*)in)[i];
  ushort4 u;
  u.x = f2b(v.x); u.y = f2b(v.y); u.z = f2b(v.z); u.w = f2b(v.w);
  ((ushort4*)(out + (size_t)blockIdx.y * 4194304))[i] = u;
}

__global__ __launch_bounds__(256) void conv_w3(const float* __restrict__ a,
                                               const float* __restrict__ b,
                                               const float* __restrict__ c,
                                               unsigned short* __restrict__ out) {
  __shared__ float T[64][65];
  const float* in = (blockIdx.y == 0) ? a : ((blockIdx.y == 1) ? b : c);
  const int t = threadIdx.x, rr = t >> 4, cc = t & 15;
  const int h = blockIdx.x >> 4, d0 = (blockIdx.x & 15) << 6;
#pragma unroll
  for (int it = 0; it < 4; ++it) {
    int dl = it * 16 + rr;
    float4 v = *(const float4*)&in[(size_t)h * 65536 + (size_t)(d0 + dl) * 64 + cc * 4];
    T[dl][cc * 4 + 0] = v.x; T[dl][cc * 4 + 1] = v.y;
    T[dl][cc * 4 + 2] = v.z; T[dl][cc * 4 + 3] = v.w;
  }
  __syncthreads();
  unsigned short* ob = out + (size_t)blockIdx.y * 1048576;
#pragma unroll
  for (int it = 0; it < 4; ++it) {
    int e = it * 16 + rr;
    ushort4 u;
    u.x = f2b(T[cc * 4 + 0][e]); u.y = f2b(T[cc * 4 + 1][e]);
    u.z = f2b(T[cc * 4 + 2][e]); u.w = f2b(T[cc * 4 + 3][e]);
    *(ushort4*)&ob[(size_t)(h * 64 + e) * 1024 + d0 + cc * 4] = u;
  }
}

__global__ __launch_bounds__(256) void conv_wo(const float* __restrict__ in,
                                               unsigned short* __restrict__ out) {
  __shared__ float T[64][65];
  const int t = threadIdx.x, rr = t >> 4, cc = t & 15;
  const int r0 = (blockIdx.x & 15) << 6;
  const int c0 = (blockIdx.x >> 4) << 6;
#pragma unroll
  for (int it = 0; it < 4; ++it) {
    int rl = it * 16 + rr;
    float4 v = *(const float4*)&in[(size_t)(r0 + rl) * 1024 + c0 + cc * 4];
    T[rl][cc * 4 + 0] = v.x; T[rl][cc * 4 + 1] = v.y;
    T[rl][cc * 4 + 2] = v.z; T[rl][cc * 4 + 3] = v.w;
  }
  __syncthreads();
#pragma unroll
  for (int it = 0; it < 4; ++it) {
    int dl = it * 16 + rr;
    ushort4 u;
    u.x = f2b(T[cc * 4 + 0][dl]); u.y = f2b(T[cc * 4 + 1][dl]);
    u.z = f2b(T[cc * 4 + 2][dl]); u.w = f2b(T[cc * 4 + 3][dl]);
    *(ushort4*)&out[(size_t)(c0 + dl) * 1024 + r0 + cc * 4] = u;
  }
}

// ---------------------------------------------------------------------------
// GEMM 128x128 tile, XCD-swizzled 1D grid, double-buffered LDS.
// 1D block L: x = L/(32*nz); r = L%(32*nz); y = r/nz; z = r%nz.
//   -> all x-tiles of an A-panel (y,z) share L%8 -> same XCD.
// qkv=1: z=0 q (mode1,qscale), z=1 k (mode1), z=2 v (mode2 [b,h,e,s]).
// qkv=0: fp32 [m][n] + bias.
// ---------------------------------------------------------------------------
__global__ __launch_bounds__(256) void gemm128(
    const short* __restrict__ A0, const short* __restrict__ A1,
    const short* __restrict__ A2, const short* __restrict__ B0,
    const short* __restrict__ B1, const short* __restrict__ B2,
    const float* __restrict__ bias0, const float* __restrict__ bias1,
    const float* __restrict__ bias2, unsigned short* __restrict__ ob0,
    unsigned short* __restrict__ ob1, unsigned short* __restrict__ ob2,
    float* __restrict__ outf, int qkv, float qscale) {
  __shared__ short As[2][128 * 32];
  __shared__ short Bs[2][128 * 32];

  const int nz = qkv ? 3 : 1;
  const int ngroups = 32 * nz;
  const int L = blockIdx.x;
  const int x = L / ngroups;
  const int r = L - x * ngroups;
  const int y = r / nz;
  const int z = r - y * nz;

  const short* A = (z == 0) ? A0 : (z == 1) ? A1 : A2;
  const short* Bt = (z == 0) ? B0 : (z == 1) ? B1 : B2;

  const int tid = threadIdx.x;
  const int lane = tid & 63, w = tid >> 6;
  const int quad = lane >> 4, col = lane & 15;
  const int m0 = y * 128, n0 = x * 128;
  const int wm = (w >> 1) * 64, wn = (w & 1) * 64;

  floatx4 acc[4][4] = {};

  const int lr = lane >> 2, gc = (lane & 3) ^ ((lane >> 3) & 3);
  const short* ga = A + (size_t)(m0 + w * 32 + lr) * 1024 + gc * 8;
  const short* gb = Bt + (size_t)(n0 + w * 32 + lr) * 1024 + gc * 8;
  const int lofs = (w * 32) * 32;
  const int asw = (col >> 1) & 3;

  // preload tile k0=0 into buffer 0
  async_copy16(&As[0][lofs], ga);
  async_copy16(&As[0][lofs + 16 * 32], ga + 16 * 1024);
  async_copy16(&Bs[0][lofs], gb);
  async_copy16(&Bs[0][lofs + 16 * 32], gb + 16 * 1024);

  int p = 0;
  for (int k0 = 0; k0 < 1024; k0 += 32) {
    __syncthreads();  // drains this tile's DMA; frees other buffer
    if (k0 + 32 < 1024) {
      const short* ga2 = ga + (k0 + 32);
      const short* gb2 = gb + (k0 + 32);
      async_copy16(&As[p ^ 1][lofs], ga2);
      async_copy16(&As[p ^ 1][lofs + 16 * 32], ga2 + 16 * 1024);
      async_copy16(&Bs[p ^ 1][lofs], gb2);
      async_copy16(&Bs[p ^ 1][lofs + 16 * 32], gb2 + 16 * 1024);
    }
    short8 af[4], bf[4];
#pragma unroll
    for (int mi = 0; mi < 4; ++mi)
      af[mi] = *(const short8*)&As[p][(wm + mi * 16 + col) * 32 + ((quad ^ asw) * 8)];
#pragma unroll
    for (int nj = 0; nj < 4; ++nj)
      bf[nj] = *(const short8*)&Bs[p][(wn + nj * 16 + col) * 32 + ((quad ^ asw) * 8)];
#pragma unroll
    for (int mi = 0; mi < 4; ++mi)
#pragma unroll
      for (int nj = 0; nj < 4; ++nj)
        acc[mi][nj] = MFMA16(af[mi], bf[nj], acc[mi][nj]);
    p ^= 1;
  }

  const float* bias = (z == 0) ? bias0 : (z == 1) ? bias1 : bias2;
  unsigned short* outb = (z == 0) ? ob0 : (z == 1) ? ob1 : ob2;
  const int mode = qkv ? ((z == 2) ? 2 : 1) : 0;
  const float scale = (qkv && z == 0) ? qscale : 1.0f;

  float bv[4];
#pragma unroll
  for (int nj = 0; nj < 4; ++nj) bv[nj] = bias[n0 + wn + nj * 16 + col];

  if (mode == 2) {
#pragma unroll
    for (int mi = 0; mi < 4; ++mi)
#pragma unroll
      for (int nj = 0; nj < 4; ++nj) {
        int m = m0 + wm + mi * 16 + quad * 4;
        int n = n0 + wn + nj * 16 + col;
        int bb = m >> 11, s = m & 2047, h = n >> 6, e = n & 63;
        ushort4 u;
        u.x = f2b(acc[mi][nj][0] + bv[nj]);
        u.y = f2b(acc[mi][nj][1] + bv[nj]);
        u.z = f2b(acc[mi][nj][2] + bv[nj]);
        u.w = f2b(acc[mi][nj][3] + bv[nj]);
        *(ushort4*)&outb[(((size_t)bb * 16 + h) * 64 + e) * 2048 + s] = u;
      }
  } else {
#pragma unroll
    for (int mi = 0; mi < 4; ++mi)
#pragma unroll
      for (int nj = 0; nj < 4; ++nj) {
        floatx4 v;
#pragma unroll
        for (int rr = 0; rr < 4; ++rr) v[rr] = (acc[mi][nj][rr] + bv[nj]) * scale;
        xpose4(v, lane);
        int m = m0 + wm + mi * 16 + quad * 4 + (col & 3);
        int nb = n0 + wn + nj * 16 + (col & ~3);
        if (mode == 0) {
          *(floatx4*)&outf[(size_t)m * 1024 + nb] = v;
        } else {
          int bb = m >> 11, s = m & 2047, h = nb >> 6, e = nb & 63;
          ushort4 u;
          u.x = f2b(v[0]); u.y = f2b(v[1]); u.z = f2b(v[2]); u.w = f2b(v[3]);
          *(ushort4*)&outb[(((size_t)bb * 16 + h) * 2048 + s) * 64 + e] = u;
        }
      }
  }
}

// ---------------------------------------------------------------------------
// Flash attention (causal), S^T formulation, 64 q/block, double-buffered K/V,
// PV via K=16 MFMA (P^T C-layout == 16x16x16 B-frag layout).
// ---------------------------------------------------------------------------
#if !HAVE_K16
__device__ __forceinline__ void exchange4(const unsigned int* u01,
                                          const unsigned int* u23, int srcA,
                                          int srcB, bool hiq, short8& pf0,
                                          short8& pf1) {
  unsigned int xA0 = (unsigned int)__shfl((int)u01[0], srcA, 64);
  unsigned int xA1 = (unsigned int)__shfl((int)u01[1], srcA, 64);
  unsigned int yA0 = (unsigned int)__shfl((int)u23[0], srcA, 64);
  unsigned int yA1 = (unsigned int)__shfl((int)u23[1], srcA, 64);
  unsigned int xB0 = (unsigned int)__shfl((int)u01[0], srcB, 64);
  unsigned int xB1 = (unsigned int)__shfl((int)u01[1], srcB, 64);
  unsigned int yB0 = (unsigned int)__shfl((int)u23[0], srcB, 64);
  unsigned int yB1 = (unsigned int)__shfl((int)u23[1], srcB, 64);
  uintx4 v0;
  v0.x = hiq ? xA1 : xA0; v0.y = hiq ? yA1 : yA0;
  v0.z = hiq ? xB1 : xB0; v0.w = hiq ? yB1 : yB0;
  pf0 = __builtin_bit_cast(short8, v0);
  xA0 = (unsigned int)__shfl((int)u01[2], srcA, 64);
  xA1 = (unsigned int)__shfl((int)u01[3], srcA, 64);
  yA0 = (unsigned int)__shfl((int)u23[2], srcA, 64);
  yA1 = (unsigned int)__shfl((int)u23[3], srcA, 64);
  xB0 = (unsigned int)__shfl((int)u01[2], srcB, 64);
  xB1 = (unsigned int)__shfl((int)u01[3], srcB, 64);
  yB0 = (unsigned int)__shfl((int)u23[2], srcB, 64);
  yB1 = (unsigned int)__shfl((int)u23[3], srcB, 64);
  uintx4 v1;
  v1.x = hiq ? xA1 : xA0; v1.y = hiq ? yA1 : yA0;
  v1.z = hiq ? xB1 : xB0; v1.w = hiq ? yB1 : yB0;
  pf1 = __builtin_bit_cast(short8, v1);
}
#endif

__device__ __forceinline__ void stage_kv(short* Kbuf, short* Vbuf,
                                         const short* kg, const short* vg,
                                         int kv0, int w, int slr, int sgc) {
  const short* kr = kg + (size_t)(kv0 + w * 16 + slr) * 64 + sgc * 8;
  async_copy16(&Kbuf[(w * 16) * 64], kr);
  async_copy16(&Kbuf[(w * 16 + 8) * 64], kr + 8 * 64);
  const short* vr = vg + (size_t)(w * 16 + slr) * 2048 + kv0 + sgc * 8;
  async_copy16(&Vbuf[(w * 16) * 64], vr);
  async_copy16(&Vbuf[(w * 16 + 8) * 64], vr + 8 * 2048);
}

__global__ __launch_bounds__(256) void attn(const short* __restrict__ q,
                                            const short* __restrict__ k,
                                            const short* __restrict__ vt,
                                            unsigned short* __restrict__ z) {
  __shared__ short Ks[2][64 * 64];  // [key][e], chunks XOR-swizzled by row&7
  __shared__ short Vs[2][64 * 64];  // [e][key], same swizzle

  const int tid = threadIdx.x;
  const int lane = tid & 63, w = tid >> 6;
  const int quad = lane >> 4, col = lane & 15;
  const int qt = 31 - (blockIdx.x >> 5), bh = blockIdx.x & 31;  // long first
  const int q0 = qt * 64, qw0 = q0 + w * 16;
  const size_t base = (size_t)bh * (2048 * 64);

  const short* qp = q + base + (size_t)(qw0 + col) * 64 + quad * 8;
  short8 bq0 = *(const short8*)qp;
  short8 bq1 = *(const short8*)(qp + 32);

  floatx4 o[4] = {};
  float m_run = -1e30f, l_run = 0.f;

  const short* kg = k + base;
  const short* vg = vt + base;
  const int ksw = col & 7;
  const int slr = lane >> 3, sgc = (lane & 7) ^ slr;
#if !HAVE_K16
  const int srcA = ((quad & 1) << 5) + col, srcB = srcA + 16;
  const bool hiq = (quad & 2) != 0;
#endif

  stage_kv(Ks[0], Vs[0], kg, vg, 0, w, slr, sgc);  // preload tile 0
  int p = 0;

  for (int t = 0; t <= qt; ++t) {
    __syncthreads();  // drains tile-t DMA; frees buffer p^1
    if (t < qt) stage_kv(Ks[p ^ 1], Vs[p ^ 1], kg, vg, (t + 1) * 64, w, slr, sgc);

    const int kv0 = t * 64;
    const bool diag = (t == qt);
    const int mtmax = diag ? w : 3;  // wave-uniform

    floatx4 st[4];
#pragma unroll
    for (int mt = 0; mt < 4; ++mt) {
      if (mt <= mtmax) {
        const short* kb = &Ks[p][(mt * 16 + col) * 64];
        short8 ka0 = *(const short8*)(kb + (quad ^ ksw) * 8);
        short8 ka1 = *(const short8*)(kb + ((quad + 4) ^ ksw) * 8);
        floatx4 a = {0.f, 0.f, 0.f, 0.f};
        a = MFMA16(ka0, bq0, a);
        a = MFMA16(ka1, bq1, a);
        if (diag && mt == mtmax) {
#pragma unroll
          for (int r = 0; r < 4; ++r)
            if (quad * 4 + r > col) a[r] = -1e9f;
        }
        st[mt] = a;
      }
    }

    float pmax = -3e38f;
#pragma unroll
    for (int mt = 0; mt < 4; ++mt)
      if (mt <= mtmax) {
#pragma unroll
        for (int r = 0; r < 4; ++r) pmax = fmaxf(pmax, st[mt][r]);
      }
    pmax = fmaxf(pmax, __shfl_xor(pmax, 16, 64));
    pmax = fmaxf(pmax, __shfl_xor(pmax, 32, 64));
    float mnew = fmaxf(m_run, pmax);
    float alpha = exp2f_fast(m_run - mnew);
    m_run = mnew;

    unsigned int u01[4], u23[4];
    float lsum = 0.f;
#pragma unroll
    for (int mt = 0; mt < 4; ++mt) {
      if (mt <= mtmax) {
        float p0 = exp2f_fast(st[mt][0] - mnew);
        float p1 = exp2f_fast(st[mt][1] - mnew);
        float p2 = exp2f_fast(st[mt][2] - mnew);
        float p3 = exp2f_fast(st[mt][3] - mnew);
        lsum += (p0 + p1) + (p2 + p3);
        u01[mt] = pack2_bf16(p0, p1);
        u23[mt] = pack2_bf16(p2, p3);
      } else {
        u01[mt] = 0u; u23[mt] = 0u;
      }
    }
    lsum += __shfl_xor(lsum, 16, 64);
    lsum += __shfl_xor(lsum, 32, 64);
    l_run = l_run * alpha + lsum;

#if HAVE_K16
    // P^T subtile C-layout is exactly the 16x16x16 B-frag layout:
    // lane n=col holds k=quad*4+j = packed {u01,u23}.
    short4v pb[4];
#pragma unroll
    for (int mt = 0; mt < 4; ++mt) {
      uint2v uu;
      uu.x = u01[mt]; uu.y = u23[mt];
      pb[mt] = __builtin_bit_cast(short4v, uu);
    }
#pragma unroll
    for (int et = 0; et < 4; ++et) {
      const short* vrow = &Vs[p][(et * 16 + col) * 64];
      floatx4 t0 = o[et];
#pragma unroll
      for (int r = 0; r < 4; ++r) t0[r] *= alpha;
#pragma unroll
      for (int mt = 0; mt < 4; ++mt) {
        if (mt <= mtmax) {
          // A-frag: V^T[e=col][key = mt*16 + quad*4 + j]
          int c = mt * 2 + (quad >> 1);
          short4v va = *(const short4v*)&vrow[((c ^ ksw) * 8) + (quad & 1) * 4];
          t0 = MFMAK16(va, pb[mt], t0);
        }
      }
      o[et] = t0;
    }
#else
    short8 pf0, pf1;
    exchange4(u01, u23, srcA, srcB, hiq, pf0, pf1);
#pragma unroll
    for (int et = 0; et < 4; ++et) {
      const short* vb = &Vs[p][(et * 16 + col) * 64];
      short8 va0 = *(const short8*)(vb + (quad ^ ksw) * 8);
      short8 va1 = *(const short8*)(vb + ((quad + 4) ^ ksw) * 8);
      floatx4 t0 = o[et];
#pragma unroll
      for (int r = 0; r < 4; ++r) t0[r] *= alpha;
      t0 = MFMA16(va0, pf0, t0);
      t0 = MFMA16(va1, pf1, t0);
      o[et] = t0;
    }
#endif
    p ^= 1;
  }

  const int b = bh >> 4, h = bh & 15;
#if __has_builtin(__builtin_amdgcn_rcpf)
  const float invl = __builtin_amdgcn_rcpf(l_run);
#else
  const float invl = 1.f / l_run;
#endif
  unsigned short* zr = z + (((size_t)b * 2048 + qw0 + col) * 16 + h) * 64;
#pragma unroll
  for (int et = 0; et < 4; ++et) {
    ushort4 u;
    u.x = f2b(o[et][0] * invl); u.y = f2b(o[et][1] * invl);
    u.z = f2b(o[et][2] * invl); u.w = f2b(o[et][3] * invl);
    *(ushort4*)&zr[et * 16 + quad * 4] = u;
  }
}

// ---------------------------------------------------------------------------
extern "C" void kernel_launch(void* const* d_in, const int* in_sizes, int n_in,
                              void* d_out, int out_size, void* d_ws, size_t ws_size,
                              hipStream_t stream) {
  (void)in_sizes; (void)n_in; (void)out_size; (void)ws_size;
  const float* Xq = (const float*)d_in[0];
  const float* Xk = (const float*)d_in[1];
  const float* Xv = (const float*)d_in[2];
  const float* WQ = (const float*)d_in[3];
  const float* WK = (const float*)d_in[4];
  const float* WV = (const float*)d_in[5];
  const float* WO = (const float*)d_in[6];
  const float* bQ = (const float*)d_in[7];
  const float* bK = (const float*)d_in[8];
  const float* bV = (const float*)d_in[9];
  const float* bO = (const float*)d_in[10];
  float* out = (float*)d_out;

  unsigned short* xqb = (unsigned short*)d_ws;
  unsigned short* xkb = xqb + 4194304;
  unsigned short* xvb = xkb + 4194304;
  unsigned short* wqt = xvb + 4194304;
  unsigned short* wkt = wqt + 1048576;
  unsigned short* wvt = wkt + 1048576;
  unsigned short* wot = wvt + 1048576;
  unsigned short* qb = wot + 1048576;
  unsigned short* kb = qb + 4194304;
  unsigned short* vtb = kb + 4194304;
  unsigned short* zb = vtb + 4194304;

  conv_x3<<<dim3(4096, 3), 256, 0, stream>>>(Xq, Xk, Xv, xqb);
  conv_w3<<<dim3(256, 3), 256, 0, stream>>>(WQ, WK, WV, wqt);
  conv_wo<<<256, 256, 0, stream>>>(WO, wot);

  const float qscale = 0.125f * 1.44269504088896f;  // 1/sqrt(64) * log2(e)
  gemm128<<<768, 256, 0, stream>>>(
      (const short*)xqb, (const short*)xkb, (const short*)xvb,
      (const short*)wqt, (const short*)wkt, (const short*)wvt, bQ, bK, bV, qb,
      kb, vtb, nullptr, 1, qscale);

  attn<<<1024, 256, 0, stream>>>((const short*)qb, (const short*)kb,
                                 (const short*)vtb, zb);

  gemm128<<<256, 256, 0, stream>>>(
      (const short*)zb, (const short*)zb, (const short*)zb, (const short*)wot,
      (const short*)wot, (const short*)wot, bO, bO, bO, nullptr, nullptr,
      nullptr, out, 0, 1.0f);
}

// Round 6
// 221.348 us; speedup vs baseline: 1.1144x; 1.1144x over previous
//
#include <hip/hip_runtime.h>
#include <stdint.h>

// ---------------------------------------------------------------------------
// AbstractAttention  B=2,S=2048,H=16,Dh=64,Dm=1024. fp32 in/out, bf16 MFMA.
// R6: GEMMs are latency-bound, not pipe-bound (all pipes <25% busy) ->
// 8-wave 512-thread blocks (24 waves/CU for QKV, 16 for the final gemm,
// which was running at 1 block/CU!); conversions fused into one dispatch.
// attn unchanged from R5.
// ---------------------------------------------------------------------------

typedef __attribute__((ext_vector_type(8))) short short8;
typedef __attribute__((ext_vector_type(4))) short short4v;
typedef __attribute__((ext_vector_type(4))) float floatx4;
typedef __attribute__((ext_vector_type(4))) unsigned int uintx4;
typedef __attribute__((ext_vector_type(2))) unsigned int uint2v;

#define MFMA16(a, b, c) __builtin_amdgcn_mfma_f32_16x16x32_bf16(a, b, c, 0, 0, 0)

#if __has_builtin(__builtin_amdgcn_mfma_f32_16x16x16bf16_1k)
#define HAVE_K16 1
#define MFMAK16(a, b, c) __builtin_amdgcn_mfma_f32_16x16x16bf16_1k(a, b, c, 0, 0, 0)
#else
#define HAVE_K16 0
#endif

__device__ __forceinline__ unsigned short f2b(float f) {  // RNE fp32->bf16
  unsigned int u = __builtin_bit_cast(unsigned int, f);
  u = (u + 0x7fffu + ((u >> 16) & 1u)) >> 16;
  return (unsigned short)u;
}
__device__ __forceinline__ float exp2f_fast(float x) {
#if __has_builtin(__builtin_amdgcn_exp2f)
  return __builtin_amdgcn_exp2f(x);
#else
  return exp2f(x);
#endif
}
__device__ __forceinline__ unsigned int pack2_bf16(float lo, float hi) {
#if __has_builtin(__builtin_amdgcn_perm)
  return __builtin_amdgcn_perm(__builtin_bit_cast(unsigned int, hi),
                               __builtin_bit_cast(unsigned int, lo), 0x07060302u);
#else
  return (__builtin_bit_cast(unsigned int, lo) >> 16) |
         (__builtin_bit_cast(unsigned int, hi) & 0xffff0000u);
#endif
}

__device__ __forceinline__ void async_copy16(void* lds, const void* g) {
  __builtin_amdgcn_global_load_lds(
      (const __attribute__((address_space(1))) unsigned int*)g,
      (__attribute__((address_space(3))) unsigned int*)lds, 16, 0, 0);
}

// 4x4 transpose across lanes within col&3 groups (2 butterfly rounds).
__device__ __forceinline__ void xpose4(floatx4& v, int lane) {
  {
    float s0 = __shfl_xor(v[1], 1, 64);
    float s1 = __shfl_xor(v[0], 1, 64);
    float s2 = __shfl_xor(v[3], 1, 64);
    float s3 = __shfl_xor(v[2], 1, 64);
    if (lane & 1) { v[0] = s0; v[2] = s2; } else { v[1] = s1; v[3] = s3; }
  }
  {
    float s0 = __shfl_xor(v[2], 2, 64);
    float s1 = __shfl_xor(v[3], 2, 64);
    float s2 = __shfl_xor(v[0], 2, 64);
    float s3 = __shfl_xor(v[1], 2, 64);
    if (lane & 2) { v[0] = s0; v[1] = s1; } else { v[2] = s2; v[3] = s3; }
  }
}

// ---------------------------------------------------------------------------
// Fused conversions: one dispatch.
// blocks [0,12288): X fp32->bf16 (3 tensors)
// blocks [12288,13056): W_{Q,K,V} [h,d,e] -> [n=h*64+e][k=d]
// blocks [13056,13312): W_O [he,d] -> [n=d][k=he]
// ---------------------------------------------------------------------------
__global__ __launch_bounds__(256) void convall(
    const float* __restrict__ Xq, const float* __restrict__ Xk,
    const float* __restrict__ Xv, const float* __restrict__ WQ,
    const float* __restrict__ WK, const float* __restrict__ WV,
    const float* __restrict__ WO, unsigned short* __restrict__ xout,
    unsigned short* __restrict__ wout, unsigned short* __restrict__ woout) {
  __shared__ float T[64][65];
  const int bid = blockIdx.x;
  const int t = threadIdx.x;
  if (bid < 12288) {
    const int yy = bid / 4096, x = bid - yy * 4096;
    const float* in = (yy == 0) ? Xq : ((yy == 1) ? Xk : Xv);
    size_t i = (size_t)x * 256 + t;
    float4 v = ((const float4*)in)[i];
    ushort4 u;
    u.x = f2b(v.x); u.y = f2b(v.y); u.z = f2b(v.z); u.w = f2b(v.w);
    ((ushort4*)(xout + (size_t)yy * 4194304))[i] = u;
    return;
  }
  const int rr = t >> 4, cc = t & 15;
  if (bid < 13056) {
    const int sub = bid - 12288;
    const int yy = sub >> 8, x = sub & 255;
    const float* in = (yy == 0) ? WQ : ((yy == 1) ? WK : WV);
    const int h = x >> 4, d0 = (x & 15) << 6;
#pragma unroll
    for (int it = 0; it < 4; ++it) {
      int dl = it * 16 + rr;
      float4 v = *(const float4*)&in[(size_t)h * 65536 + (size_t)(d0 + dl) * 64 + cc * 4];
      T[dl][cc * 4 + 0] = v.x; T[dl][cc * 4 + 1] = v.y;
      T[dl][cc * 4 + 2] = v.z; T[dl][cc * 4 + 3] = v.w;
    }
    __syncthreads();
    unsigned short* ob = wout + (size_t)yy * 1048576;
#pragma unroll
    for (int it = 0; it < 4; ++it) {
      int e = it * 16 + rr;
      ushort4 u;
      u.x = f2b(T[cc * 4 + 0][e]); u.y = f2b(T[cc * 4 + 1][e]);
      u.z = f2b(T[cc * 4 + 2][e]); u.w = f2b(T[cc * 4 + 3][e]);
      *(ushort4*)&ob[(size_t)(h * 64 + e) * 1024 + d0 + cc * 4] = u;
    }
    return;
  }
  {
    const int x = bid - 13056;
    const int r0 = (x & 15) << 6, c0 = (x >> 4) << 6;
#pragma unroll
    for (int it = 0; it < 4; ++it) {
      int rl = it * 16 + rr;
      float4 v = *(const float4*)&WO[(size_t)(r0 + rl) * 1024 + c0 + cc * 4];
      T[rl][cc * 4 + 0] = v.x; T[rl][cc * 4 + 1] = v.y;
      T[rl][cc * 4 + 2] = v.z; T[rl][cc * 4 + 3] = v.w;
    }
    __syncthreads();
#pragma unroll
    for (int it = 0; it < 4; ++it) {
      int dl = it * 16 + rr;
      ushort4 u;
      u.x = f2b(T[cc * 4 + 0][dl]); u.y = f2b(T[cc * 4 + 1][dl]);
      u.z = f2b(T[cc * 4 + 2][dl]); u.w = f2b(T[cc * 4 + 3][dl]);
      *(ushort4*)&woout[(size_t)(c0 + dl) * 1024 + r0 + cc * 4] = u;
    }
  }
}

// ---------------------------------------------------------------------------
// GEMM, 8 waves / 512 threads, TM x 128 tile, BK=32, 2-barrier, XCD swizzle.
// TM=128: waves 4(m) x 2(n), wave tile 32x64 (MI=2,NJ=4).
// TM=64 : waves 2(m) x 4(n), wave tile 32x32 (MI=2,NJ=2).
// NZ=3: z=0 q (mode1, qscale), z=1 k (mode1), z=2 v (mode2 [b,h,e,s]).
// NZ=1: fp32 [m][n] + bias (mode 0).
// ---------------------------------------------------------------------------
template <int TM, int NZ>
__global__ __launch_bounds__(512, (TM == 128) ? 6 : 4) void gemm512(
    const short* __restrict__ A0, const short* __restrict__ A1,
    const short* __restrict__ A2, const short* __restrict__ B0,
    const short* __restrict__ B1, const short* __restrict__ B2,
    const float* __restrict__ bias0, const float* __restrict__ bias1,
    const float* __restrict__ bias2, unsigned short* __restrict__ ob0,
    unsigned short* __restrict__ ob1, unsigned short* __restrict__ ob2,
    float* __restrict__ outf, float qscale) {
  constexpr int WAVES_N = (TM == 128) ? 2 : 4;
  constexpr int NJ = (TM == 128) ? 4 : 2;
  constexpr int NY = 4096 / TM;
  __shared__ short As[TM * 32];
  __shared__ short Bs[128 * 32];

  const int L = blockIdx.x;
  const int x = L / (NY * NZ);
  const int r = L - x * (NY * NZ);
  const int y = r / NZ;
  const int z = r - y * NZ;

  const short* A = (z == 0) ? A0 : (z == 1) ? A1 : A2;
  const short* Bt = (z == 0) ? B0 : (z == 1) ? B1 : B2;

  const int tid = threadIdx.x;
  const int lane = tid & 63, w = tid >> 6;
  const int quad = lane >> 4, col = lane & 15;
  const int m0 = y * TM, n0 = x * 128;
  const int wm = (w / WAVES_N) * 32, wn = (w % WAVES_N) * (NJ * 16);

  floatx4 acc[2][NJ] = {};

  const int lr = lane >> 2, gc = (lane & 3) ^ ((lane >> 3) & 3);
  const short* ga = A + (size_t)(m0 + w * 16 + lr) * 1024 + gc * 8;
  const short* gb = Bt + (size_t)(n0 + w * 16 + lr) * 1024 + gc * 8;
  const int asw = (col >> 1) & 3;
  const bool stageA = (w < TM / 16);

  for (int k0 = 0; k0 < 1024; k0 += 32) {
    if (stageA) async_copy16(&As[(w * 16) * 32], ga);
    async_copy16(&Bs[(w * 16) * 32], gb);
    ga += 32; gb += 32;
    __syncthreads();
    short8 af[2], bf[NJ];
#pragma unroll
    for (int mi = 0; mi < 2; ++mi)
      af[mi] = *(const short8*)&As[(wm + mi * 16 + col) * 32 + ((quad ^ asw) * 8)];
#pragma unroll
    for (int nj = 0; nj < NJ; ++nj)
      bf[nj] = *(const short8*)&Bs[(wn + nj * 16 + col) * 32 + ((quad ^ asw) * 8)];
#pragma unroll
    for (int mi = 0; mi < 2; ++mi)
#pragma unroll
      for (int nj = 0; nj < NJ; ++nj)
        acc[mi][nj] = MFMA16(af[mi], bf[nj], acc[mi][nj]);
    __syncthreads();
  }

  const float* bias = (z == 0) ? bias0 : (z == 1) ? bias1 : bias2;
  unsigned short* outb = (z == 0) ? ob0 : (z == 1) ? ob1 : ob2;
  const int mode = (NZ == 3) ? ((z == 2) ? 2 : 1) : 0;
  const float scale = (NZ == 3 && z == 0) ? qscale : 1.0f;

  float bv[NJ];
#pragma unroll
  for (int nj = 0; nj < NJ; ++nj) bv[nj] = bias[n0 + wn + nj * 16 + col];

  if (mode == 2) {
#pragma unroll
    for (int mi = 0; mi < 2; ++mi)
#pragma unroll
      for (int nj = 0; nj < NJ; ++nj) {
        int m = m0 + wm + mi * 16 + quad * 4;
        int n = n0 + wn + nj * 16 + col;
        int bb = m >> 11, s = m & 2047, h = n >> 6, e = n & 63;
        ushort4 u;
        u.x = f2b(acc[mi][nj][0] + bv[nj]);
        u.y = f2b(acc[mi][nj][1] + bv[nj]);
        u.z = f2b(acc[mi][nj][2] + bv[nj]);
        u.w = f2b(acc[mi][nj][3] + bv[nj]);
        *(ushort4*)&outb[(((size_t)bb * 16 + h) * 64 + e) * 2048 + s] = u;
      }
  } else {
#pragma unroll
    for (int mi = 0; mi < 2; ++mi)
#pragma unroll
      for (int nj = 0; nj < NJ; ++nj) {
        floatx4 v;
#pragma unroll
        for (int rr = 0; rr < 4; ++rr) v[rr] = (acc[mi][nj][rr] + bv[nj]) * scale;
        xpose4(v, lane);
        int m = m0 + wm + mi * 16 + quad * 4 + (col & 3);
        int nb = n0 + wn + nj * 16 + (col & ~3);
        if (mode == 0) {
          *(floatx4*)&outf[(size_t)m * 1024 + nb] = v;
        } else {
          int bb = m >> 11, s = m & 2047, h = nb >> 6, e = nb & 63;
          ushort4 u;
          u.x = f2b(v[0]); u.y = f2b(v[1]); u.z = f2b(v[2]); u.w = f2b(v[3]);
          *(ushort4*)&outb[(((size_t)bb * 16 + h) * 2048 + s) * 64 + e] = u;
        }
      }
  }
}

// ---------------------------------------------------------------------------
// Flash attention (causal), S^T formulation, 64 q/block, double-buffered K/V,
// PV via K=16 MFMA (P^T C-layout == 16x16x16 B-frag layout).  (R5, unchanged)
// ---------------------------------------------------------------------------
#if !HAVE_K16
__device__ __forceinline__ void exchange4(const unsigned int* u01,
                                          const unsigned int* u23, int srcA,
                                          int srcB, bool hiq, short8& pf0,
                                          short8& pf1) {
  unsigned int xA0 = (unsigned int)__shfl((int)u01[0], srcA, 64);
  unsigned int xA1 = (unsigned int)__shfl((int)u01[1], srcA, 64);
  unsigned int yA0 = (unsigned int)__shfl((int)u23[0], srcA, 64);
  unsigned int yA1 = (unsigned int)__shfl((int)u23[1], srcA, 64);
  unsigned int xB0 = (unsigned int)__shfl((int)u01[0], srcB, 64);
  unsigned int xB1 = (unsigned int)__shfl((int)u01[1], srcB, 64);
  unsigned int yB0 = (unsigned int)__shfl((int)u23[0], srcB, 64);
  unsigned int yB1 = (unsigned int)__shfl((int)u23[1], srcB, 64);
  uintx4 v0;
  v0.x = hiq ? xA1 : xA0; v0.y = hiq ? yA1 : yA0;
  v0.z = hiq ? xB1 : xB0; v0.w = hiq ? yB1 : yB0;
  pf0 = __builtin_bit_cast(short8, v0);
  xA0 = (unsigned int)__shfl((int)u01[2], srcA, 64);
  xA1 = (unsigned int)__shfl((int)u01[3], srcA, 64);
  yA0 = (unsigned int)__shfl((int)u23[2], srcA, 64);
  yA1 = (unsigned int)__shfl((int)u23[3], srcA, 64);
  xB0 = (unsigned int)__shfl((int)u01[2], srcB, 64);
  xB1 = (unsigned int)__shfl((int)u01[3], srcB, 64);
  yB0 = (unsigned int)__shfl((int)u23[2], srcB, 64);
  yB1 = (unsigned int)__shfl((int)u23[3], srcB, 64);
  uintx4 v1;
  v1.x = hiq ? xA1 : xA0; v1.y = hiq ? yA1 : yA0;
  v1.z = hiq ? xB1 : xB0; v1.w = hiq ? yB1 : yB0;
  pf1 = __builtin_bit_cast(short8, v1);
}
#endif

__device__ __forceinline__ void stage_kv(short* Kbuf, short* Vbuf,
                                         const short* kg, const short* vg,
                                         int kv0, int w, int slr, int sgc) {
  const short* kr = kg + (size_t)(kv0 + w * 16 + slr) * 64 + sgc * 8;
  async_copy16(&Kbuf[(w * 16) * 64], kr);
  async_copy16(&Kbuf[(w * 16 + 8) * 64], kr + 8 * 64);
  const short* vr = vg + (size_t)(w * 16 + slr) * 2048 + kv0 + sgc * 8;
  async_copy16(&Vbuf[(w * 16) * 64], vr);
  async_copy16(&Vbuf[(w * 16 + 8) * 64], vr + 8 * 2048);
}

__global__ __launch_bounds__(256) void attn(const short* __restrict__ q,
                                            const short* __restrict__ k,
                                            const short* __restrict__ vt,
                                            unsigned short* __restrict__ z) {
  __shared__ short Ks[2][64 * 64];
  __shared__ short Vs[2][64 * 64];

  const int tid = threadIdx.x;
  const int lane = tid & 63, w = tid >> 6;
  const int quad = lane >> 4, col = lane & 15;
  const int qt = 31 - (blockIdx.x >> 5), bh = blockIdx.x & 31;
  const int q0 = qt * 64, qw0 = q0 + w * 16;
  const size_t base = (size_t)bh * (2048 * 64);

  const short* qp = q + base + (size_t)(qw0 + col) * 64 + quad * 8;
  short8 bq0 = *(const short8*)qp;
  short8 bq1 = *(const short8*)(qp + 32);

  floatx4 o[4] = {};
  float m_run = -1e30f, l_run = 0.f;

  const short* kg = k + base;
  const short* vg = vt + base;
  const int ksw = col & 7;
  const int slr = lane >> 3, sgc = (lane & 7) ^ slr;
#if !HAVE_K16
  const int srcA = ((quad & 1) << 5) + col, srcB = srcA + 16;
  const bool hiq = (quad & 2) != 0;
#endif

  stage_kv(Ks[0], Vs[0], kg, vg, 0, w, slr, sgc);
  int p = 0;

  for (int t = 0; t <= qt; ++t) {
    __syncthreads();
    if (t < qt) stage_kv(Ks[p ^ 1], Vs[p ^ 1], kg, vg, (t + 1) * 64, w, slr, sgc);

    const bool diag = (t == qt);
    const int mtmax = diag ? w : 3;

    floatx4 st[4];
#pragma unroll
    for (int mt = 0; mt < 4; ++mt) {
      if (mt <= mtmax) {
        const short* kb = &Ks[p][(mt * 16 + col) * 64];
        short8 ka0 = *(const short8*)(kb + (quad ^ ksw) * 8);
        short8 ka1 = *(const short8*)(kb + ((quad + 4) ^ ksw) * 8);
        floatx4 a = {0.f, 0.f, 0.f, 0.f};
        a = MFMA16(ka0, bq0, a);
        a = MFMA16(ka1, bq1, a);
        if (diag && mt == mtmax) {
#pragma unroll
          for (int r = 0; r < 4; ++r)
            if (quad * 4 + r > col) a[r] = -1e9f;
        }
        st[mt] = a;
      }
    }

    float pmax = -3e38f;
#pragma unroll
    for (int mt = 0; mt < 4; ++mt)
      if (mt <= mtmax) {
#pragma unroll
        for (int r = 0; r < 4; ++r) pmax = fmaxf(pmax, st[mt][r]);
      }
    pmax = fmaxf(pmax, __shfl_xor(pmax, 16, 64));
    pmax = fmaxf(pmax, __shfl_xor(pmax, 32, 64));
    float mnew = fmaxf(m_run, pmax);
    float alpha = exp2f_fast(m_run - mnew);
    m_run = mnew;

    unsigned int u01[4], u23[4];
    float lsum = 0.f;
#pragma unroll
    for (int mt = 0; mt < 4; ++mt) {
      if (mt <= mtmax) {
        float p0 = exp2f_fast(st[mt][0] - mnew);
        float p1 = exp2f_fast(st[mt][1] - mnew);
        float p2 = exp2f_fast(st[mt][2] - mnew);
        float p3 = exp2f_fast(st[mt][3] - mnew);
        lsum += (p0 + p1) + (p2 + p3);
        u01[mt] = pack2_bf16(p0, p1);
        u23[mt] = pack2_bf16(p2, p3);
      } else {
        u01[mt] = 0u; u23[mt] = 0u;
      }
    }
    lsum += __shfl_xor(lsum, 16, 64);
    lsum += __shfl_xor(lsum, 32, 64);
    l_run = l_run * alpha + lsum;

#if HAVE_K16
    short4v pb[4];
#pragma unroll
    for (int mt = 0; mt < 4; ++mt) {
      uint2v uu;
      uu.x = u01[mt]; uu.y = u23[mt];
      pb[mt] = __builtin_bit_cast(short4v, uu);
    }
#pragma unroll
    for (int et = 0; et < 4; ++et) {
      const short* vrow = &Vs[p][(et * 16 + col) * 64];
      floatx4 t0 = o[et];
#pragma unroll
      for (int r = 0; r < 4; ++r) t0[r] *= alpha;
#pragma unroll
      for (int mt = 0; mt < 4; ++mt) {
        if (mt <= mtmax) {
          int c = mt * 2 + (quad >> 1);
          short4v va = *(const short4v*)&vrow[((c ^ ksw) * 8) + (quad & 1) * 4];
          t0 = MFMAK16(va, pb[mt], t0);
        }
      }
      o[et] = t0;
    }
#else
    short8 pf0, pf1;
    exchange4(u01, u23, srcA, srcB, hiq, pf0, pf1);
#pragma unroll
    for (int et = 0; et < 4; ++et) {
      const short* vb = &Vs[p][(et * 16 + col) * 64];
      short8 va0 = *(const short8*)(vb + (quad ^ ksw) * 8);
      short8 va1 = *(const short8*)(vb + ((quad + 4) ^ ksw) * 8);
      floatx4 t0 = o[et];
#pragma unroll
      for (int r = 0; r < 4; ++r) t0[r] *= alpha;
      t0 = MFMA16(va0, pf0, t0);
      t0 = MFMA16(va1, pf1, t0);
      o[et] = t0;
    }
#endif
    p ^= 1;
  }

  const int b = bh >> 4, h = bh & 15;
#if __has_builtin(__builtin_amdgcn_rcpf)
  const float invl = __builtin_amdgcn_rcpf(l_run);
#else
  const float invl = 1.f / l_run;
#endif
  unsigned short* zr = z + (((size_t)b * 2048 + qw0 + col) * 16 + h) * 64;
#pragma unroll
  for (int et = 0; et < 4; ++et) {
    ushort4 u;
    u.x = f2b(o[et][0] * invl); u.y = f2b(o[et][1] * invl);
    u.z = f2b(o[et][2] * invl); u.w = f2b(o[et][3] * invl);
    *(ushort4*)&zr[et * 16 + quad * 4] = u;
  }
}

// ---------------------------------------------------------------------------
extern "C" void kernel_launch(void* const* d_in, const int* in_sizes, int n_in,
                              void* d_out, int out_size, void* d_ws, size_t ws_size,
                              hipStream_t stream) {
  (void)in_sizes; (void)n_in; (void)out_size; (void)ws_size;
  const float* Xq = (const float*)d_in[0];
  const float* Xk = (const float*)d_in[1];
  const float* Xv = (const float*)d_in[2];
  const float* WQ = (const float*)d_in[3];
  const float* WK = (const float*)d_in[4];
  const float* WV = (const float*)d_in[5];
  const float* WO = (const float*)d_in[6];
  const float* bQ = (const float*)d_in[7];
  const float* bK = (const float*)d_in[8];
  const float* bV = (const float*)d_in[9];
  const float* bO = (const float*)d_in[10];
  float* out = (float*)d_out;

  unsigned short* xqb = (unsigned short*)d_ws;
  unsigned short* xkb = xqb + 4194304;
  unsigned short* xvb = xkb + 4194304;
  unsigned short* wqt = xvb + 4194304;
  unsigned short* wkt = wqt + 1048576;
  unsigned short* wvt = wkt + 1048576;
  unsigned short* wot = wvt + 1048576;
  unsigned short* qb = wot + 1048576;
  unsigned short* kb = qb + 4194304;
  unsigned short* vtb = kb + 4194304;
  unsigned short* zb = vtb + 4194304;

  convall<<<13312, 256, 0, stream>>>(Xq, Xk, Xv, WQ, WK, WV, WO, xqb, wqt, wot);

  const float qscale = 0.125f * 1.44269504088896f;  // 1/sqrt(64) * log2(e)
  gemm512<128, 3><<<768, 512, 0, stream>>>(
      (const short*)xqb, (const short*)xkb, (const short*)xvb,
      (const short*)wqt, (const short*)wkt, (const short*)wvt, bQ, bK, bV, qb,
      kb, vtb, nullptr, qscale);

  attn<<<1024, 256, 0, stream>>>((const short*)qb, (const short*)kb,
                                 (const short*)vtb, zb);

  gemm512<64, 1><<<512, 512, 0, stream>>>(
      (const short*)zb, (const short*)zb, (const short*)zb, (const short*)wot,
      (const short*)wot, (const short*)wot, bO, bO, bO, nullptr, nullptr,
      nullptr, out, 1.0f);
}